// Round 7
// baseline (223.789 us; speedup 1.0000x reference)
//
#include <hip/hip_runtime.h>
#include <stdint.h>

#define B_ 2
#define S_ 2048
#define E_ 1024
#define H_ 16
#define D_ 64
#define R_ 16

typedef short s16x8 __attribute__((ext_vector_type(8)));
typedef float f32x4 __attribute__((ext_vector_type(4)));

#define K1_ 0.045084220027780106f   // log2(e)/32
#define K0_ -28.853900817779268f    // -20*log2(e)

// fp32 -> bf16 bits, round-to-nearest (ties away)
__device__ __forceinline__ unsigned short f2bf(float f) {
  union { float f; unsigned u; } v; v.f = f;
  return (unsigned short)((v.u + 0x8000u) >> 16);
}

// async global->LDS, 16B per lane
__device__ __forceinline__ void load_lds16(const void* g, void* l) {
  __builtin_amdgcn_global_load_lds(
      (__attribute__((address_space(1))) void*)(g),
      (__attribute__((address_space(3))) void*)(l), 16, 0, 0);
}

// ---------------- unified prep kernel ----------------
// blocks [0,4096): x fp32->bf16
// blocks [4096,4608): Wq/Wk transpose -> Wt[(which,h,d),e]  (Wq scaled by K1)
// blocks [4608,8704): fused Wv = Wvd@Wvu -> Wt[(2,h,d),e]
// blocks [8704,8716): biases (bq scaled by K1)
__global__ void k_prep(const float* __restrict__ x,
                       const float* __restrict__ Wq, const float* __restrict__ Wk,
                       const float* __restrict__ Wvd, const float* __restrict__ Wvu,
                       const float* __restrict__ bq, const float* __restrict__ bk,
                       const float* __restrict__ bvd, const float* __restrict__ bvu,
                       unsigned short* __restrict__ xb, unsigned short* __restrict__ Wt,
                       float* __restrict__ ball) {
  __shared__ float T[64][65];
  const int blk = blockIdx.x;
  const int t = threadIdx.x;
  if (blk < 4096) {
    int i = (blk * 256 + t) * 4;
    float4 v = *(const float4*)(x + i);
    ushort4 o;
    o.x = f2bf(v.x); o.y = f2bf(v.y); o.z = f2bf(v.z); o.w = f2bf(v.w);
    *(ushort4*)(xb + i) = o;
  } else if (blk < 4608) {
    const int bb = blk - 4096;
    const int which = bb >> 8;
    const int h = (bb >> 4) & 15;
    const int et = bb & 15;
    const float scl = which ? 1.f : K1_;
    const float* src = (which ? Wk : Wq) + (h * E_ + et * 64) * D_;
#pragma unroll
    for (int pr = 0; pr < 4; ++pr) {
      const int row = pr * 16 + (t >> 4);
      const int col = (t & 15) * 4;
      float4 v = *(const float4*)(src + row * 64 + col);
      T[row][col] = v.x; T[row][col + 1] = v.y; T[row][col + 2] = v.z; T[row][col + 3] = v.w;
    }
    __syncthreads();
#pragma unroll
    for (int pr = 0; pr < 4; ++pr) {
      const int d = pr * 16 + (t >> 4);
      const int ec = (t & 15) * 4;
      ushort4 o;
      o.x = f2bf(T[ec][d] * scl); o.y = f2bf(T[ec + 1][d] * scl);
      o.z = f2bf(T[ec + 2][d] * scl); o.w = f2bf(T[ec + 3][d] * scl);
      *(ushort4*)(Wt + ((which << 10) + h * 64 + d) * 1024 + et * 64 + ec) = o;
    }
  } else if (blk < 8704) {
    const int idx = (blk - 4608) * 256 + t;  // 1M
    const int row = idx >> 10;                // h*64+d
    const int e = idx & 1023;
    const int h = row >> 6, d = row & 63;
    const float4* wd4 = (const float4*)(Wvd + (h << 14) + e * 16);
    const float* wu = Wvu + h * R_ * D_ + d;
    float acc = 0.f;
#pragma unroll
    for (int r4 = 0; r4 < 4; ++r4) {
      float4 a = wd4[r4];
      acc += a.x * wu[(r4 * 4 + 0) * 64];
      acc += a.y * wu[(r4 * 4 + 1) * 64];
      acc += a.z * wu[(r4 * 4 + 2) * 64];
      acc += a.w * wu[(r4 * 4 + 3) * 64];
    }
    Wt[(2048 + row) * 1024 + e] = f2bf(acc);
  } else {
    int n = (blk - 8704) * 256 + t;  // 3072
    int which = n >> 10;
    int hd = n & 1023;
    int h = hd >> 6, d = hd & 63;
    float v;
    if (which == 0) v = bq[hd] * K1_;
    else if (which == 1) v = bk[hd];
    else {
      v = bvu[hd];
#pragma unroll
      for (int r = 0; r < R_; ++r) v += bvd[h * R_ + r] * Wvu[(h * R_ + r) * D_ + d];
    }
    ball[n] = v;
  }
}

// ---------------- fused QKV GEMM, double-buffered single-barrier K-loop ------
// cols [0,1024): Q*K1 -> (bh, s, d); [1024,2048): K -> (bh, s, d);
// [2048,3072): V -> transposed (bh, d, s)
// Q/K blocks compute C^T (operand-swapped MFMA) so stores are ushort4.

__global__ __launch_bounds__(256, 3) void k_gemm_qkv(
    const unsigned short* __restrict__ X, const unsigned short* __restrict__ Wt,
    const float* __restrict__ ball,
    unsigned short* __restrict__ Qb, unsigned short* __restrict__ Kb,
    unsigned short* __restrict__ Vb) {
  __shared__ unsigned short As[2][128 * 32];
  __shared__ unsigned short Bs[2][128 * 32];
  const int tid = threadIdx.x;
  const int lane = tid & 63, wave = tid >> 6;
  const int quad = lane >> 4, l16 = lane & 15;
  const int mBase = blockIdx.y * 128, nBase = blockIdx.x * 128;
  const int wm = (wave & 1) * 64, wn = (wave >> 1) * 64;
  const int lrow = lane >> 2, lcol = (lane & 3) * 8;
  const int which = nBase >> 10;  // block-uniform: 0=Q 1=K 2=V
  const bool qk = (which != 2);

  f32x4 acc[4][4];
#pragma unroll
  for (int mi = 0; mi < 4; ++mi)
#pragma unroll
    for (int ni = 0; ni < 4; ++ni) acc[mi][ni] = (f32x4){0.f, 0.f, 0.f, 0.f};

  // prologue: stage k0=0 into buffer 0
#pragma unroll
  for (int i = 0; i < 2; ++i) {
    const int r0 = __builtin_amdgcn_readfirstlane((wave + i * 4) * 16);
    load_lds16(X + (mBase + r0 + lrow) * E_ + lcol, &As[0][r0 * 32]);
    load_lds16(Wt + (nBase + r0 + lrow) * E_ + lcol, &Bs[0][r0 * 32]);
  }

  int buf = 0;
  for (int k0 = 0; k0 < E_; k0 += 32) {
    __syncthreads();  // buf ready (DMA drained), prior reads of buf^1 done
    if (k0 + 32 < E_) {
#pragma unroll
      for (int i = 0; i < 2; ++i) {
        const int r0 = __builtin_amdgcn_readfirstlane((wave + i * 4) * 16);
        load_lds16(X + (mBase + r0 + lrow) * E_ + k0 + 32 + lcol, &As[buf ^ 1][r0 * 32]);
        load_lds16(Wt + (nBase + r0 + lrow) * E_ + k0 + 32 + lcol, &Bs[buf ^ 1][r0 * 32]);
      }
    }
    s16x8 af[4], bfr[4];
#pragma unroll
    for (int mi = 0; mi < 4; ++mi)
      af[mi] = *(const s16x8*)&As[buf][(wm + mi * 16 + l16) * 32 + quad * 8];
#pragma unroll
    for (int ni = 0; ni < 4; ++ni)
      bfr[ni] = *(const s16x8*)&Bs[buf][(wn + ni * 16 + l16) * 32 + quad * 8];
    if (qk) {  // C^T: D[row=d-tile][col=s-tile]
#pragma unroll
      for (int mi = 0; mi < 4; ++mi)
#pragma unroll
        for (int ni = 0; ni < 4; ++ni)
          acc[mi][ni] = __builtin_amdgcn_mfma_f32_16x16x32_bf16(bfr[ni], af[mi], acc[mi][ni], 0, 0, 0);
    } else {
#pragma unroll
      for (int mi = 0; mi < 4; ++mi)
#pragma unroll
        for (int ni = 0; ni < 4; ++ni)
          acc[mi][ni] = __builtin_amdgcn_mfma_f32_16x16x32_bf16(af[mi], bfr[ni], acc[mi][ni], 0, 0, 0);
    }
    buf ^= 1;
  }

  if (qk) {
    unsigned short* dstBase = (which == 0) ? Qb : Kb;
#pragma unroll
    for (int mi = 0; mi < 4; ++mi) {
      const int m0 = mBase + wm + mi * 16 + l16;   // s index (col = l16)
      const int b = m0 >> 11;
      const int s = m0 & 2047;
#pragma unroll
      for (int ni = 0; ni < 4; ++ni) {
        const int n = nBase + wn + ni * 16 + quad * 4;  // 4 consecutive d (rows)
        const int nh = n & 1023;
        const int h = nh >> 6, d0 = nh & 63;
        const float4 bb = *(const float4*)&ball[n];
        const int bh = b * H_ + h;
        ushort4 pk;
        pk.x = f2bf(acc[mi][ni][0] + bb.x);
        pk.y = f2bf(acc[mi][ni][1] + bb.y);
        pk.z = f2bf(acc[mi][ni][2] + bb.z);
        pk.w = f2bf(acc[mi][ni][3] + bb.w);
        *(ushort4*)(dstBase + (bh * S_ + s) * D_ + d0) = pk;
      }
    }
  } else {
#pragma unroll
    for (int ni = 0; ni < 4; ++ni) {
      const int n = nBase + wn + ni * 16 + l16;
      const int nh = n & 1023;
      const int h = nh >> 6, d = nh & 63;
      const float bias = ball[n];
#pragma unroll
      for (int mi = 0; mi < 4; ++mi) {
        const int m0 = mBase + wm + mi * 16 + quad * 4;  // 4 consecutive s (rows)
        const int b = m0 >> 11;
        const int s = m0 & 2047;
        const int bh = b * H_ + h;
        ushort4 pk;
        pk.x = f2bf(acc[mi][ni][0] + bias);
        pk.y = f2bf(acc[mi][ni][1] + bias);
        pk.z = f2bf(acc[mi][ni][2] + bias);
        pk.w = f2bf(acc[mi][ni][3] + bias);
        *(ushort4*)(Vb + (bh * D_ + d) * S_ + s) = pk;  // transposed store
      }
    }
  }
}

// ---------------- flash attention (anti-causal: attend t >= s) ----------------
// Wave owns 16 q-rows. K double-buffered in LDS (DMA prefetch after the single
// per-iter barrier); V fragments loaded global->VGPR BEFORE the barrier so the
// compiler's pre-barrier vmcnt(0) drain covers them (V latency ~ free).
// 4 blocks/CU, balanced (qt,bh) mapping -> 66 tile-units per CU.
// Fixed-max softmax: Q pre-scaled by K1, QK MFMA C-initialized with K0.

__global__ __launch_bounds__(256, 4) void k_attn(
    const unsigned short* __restrict__ Qb, const unsigned short* __restrict__ Kb,
    const unsigned short* __restrict__ Vb, float* __restrict__ out) {
  __shared__ unsigned short Ks[2][2 * 64 * 32];   // [buf][64 k-rows x 64 d]
  __shared__ unsigned short Ps[4][2][16][40];     // [wave][kc][q-row][32 t + pad]
  const int tid = threadIdx.x;
  const int lane = tid & 63, wave = tid >> 6;
  const int quad = lane >> 4, l16 = lane & 15;
  // balanced block mapping
  const int chunk = blockIdx.x >> 8;
  const int j = blockIdx.x & 255;
  int qt = j >> 3;
  if (chunk & 1) qt = 31 - qt;
  const int bh = (j & 7) + 8 * chunk;
  const int q0 = qt * 64;
  const int lrow = lane >> 2, lcol = (lane & 3) * 8;
  const int r0 = __builtin_amdgcn_readfirstlane(wave * 16);
  const f32x4 kvec = {K0_, K0_, K0_, K0_};

  s16x8 qf[2];
  {
    const unsigned short* qp = Qb + (bh * S_ + q0 + wave * 16 + l16) * D_ + quad * 8;
    qf[0] = *(const s16x8*)qp;
    qf[1] = *(const s16x8*)(qp + 32);
  }
  f32x4 o[4];
#pragma unroll
  for (int dc = 0; dc < 4; ++dc) o[dc] = (f32x4){0.f, 0.f, 0.f, 0.f};
  float l_acc[4] = {0.f, 0.f, 0.f, 0.f};

  // prologue: stage K tile qt into buffer 0
#pragma unroll
  for (int hdc = 0; hdc < 2; ++hdc)
    load_lds16(Kb + (bh * S_ + q0 + r0 + lrow) * D_ + hdc * 32 + lcol,
               &Ks[0][hdc * 2048 + r0 * 32]);

  int buf = 0;
  for (int kt = qt; kt < S_ / 64; ++kt) {
    // V fragments for THIS tile, straight from L2 (drained by the barrier)
    s16x8 vb[2][4];
#pragma unroll
    for (int kc = 0; kc < 2; ++kc)
#pragma unroll
      for (int dc = 0; dc < 4; ++dc)
        vb[kc][dc] = *(const s16x8*)(Vb +
            (bh * D_ + dc * 16 + l16) * S_ + kt * 64 + kc * 32 + quad * 8);

    __syncthreads();  // Ks[buf] DMA done, vb loaded, prior reads of buf^1 done
    if (kt + 1 < S_ / 64) {
      const int k0n = (kt + 1) * 64;
#pragma unroll
      for (int hdc = 0; hdc < 2; ++hdc)
        load_lds16(Kb + (bh * S_ + k0n + r0 + lrow) * D_ + hdc * 32 + lcol,
                   &Ks[buf ^ 1][hdc * 2048 + r0 * 32]);
    }

    // raw scores: 16 q-rows x 64 keys, C-init with K0
    f32x4 sc[4];
#pragma unroll
    for (int tc = 0; tc < 4; ++tc) {
      f32x4 a = __builtin_amdgcn_mfma_f32_16x16x32_bf16(
          qf[0], *(const s16x8*)&Ks[buf][(tc * 16 + l16) * 32 + quad * 8], kvec, 0, 0, 0);
      sc[tc] = __builtin_amdgcn_mfma_f32_16x16x32_bf16(
          qf[1], *(const s16x8*)&Ks[buf][2048 + (tc * 16 + l16) * 32 + quad * 8], a, 0, 0, 0);
    }

    if (kt == qt) {  // diagonal tile: mask t < q
#pragma unroll
      for (int tc = 0; tc < 4; ++tc)
#pragma unroll
        for (int r = 0; r < 4; ++r) {
          const int t = tc * 16 + l16;
          const int q = wave * 16 + quad * 4 + r;
          if (t < q) sc[tc][r] = -200.f;
        }
    }

    // p = exp2(sc); accumulate l; store bf16 P (truncation)
#pragma unroll
    for (int tc = 0; tc < 4; ++tc)
#pragma unroll
      for (int r = 0; r < 4; ++r) {
        float p = exp2f(sc[tc][r]);
        l_acc[r] += p;
        Ps[wave][tc >> 1][quad * 4 + r][(tc & 1) * 16 + l16] =
            (unsigned short)(__float_as_uint(p) >> 16);
      }

    // PV: P A-frag from per-wave LDS (no barrier), V B-frag in regs
#pragma unroll
    for (int kc = 0; kc < 2; ++kc) {
      s16x8 pf = *(const s16x8*)&Ps[wave][kc][l16][quad * 8];
#pragma unroll
      for (int dc = 0; dc < 4; ++dc)
        o[dc] = __builtin_amdgcn_mfma_f32_16x16x32_bf16(pf, vb[kc][dc], o[dc], 0, 0, 0);
    }
    buf ^= 1;
  }

  // epilogue: reduce l over the 16 lanes holding each row's t-slices
#pragma unroll
  for (int off = 1; off < 16; off <<= 1)
#pragma unroll
    for (int r = 0; r < 4; ++r) l_acc[r] += __shfl_xor(l_acc[r], off);
  float rinv[4];
#pragma unroll
  for (int r = 0; r < 4; ++r) rinv[r] = 1.f / l_acc[r];

  const int b = bh >> 4, h = bh & 15;
#pragma unroll
  for (int dc = 0; dc < 4; ++dc)
#pragma unroll
    for (int r = 0; r < 4; ++r) {
      const int s = q0 + wave * 16 + quad * 4 + r;
      out[(b * S_ + s) * (H_ * D_) + h * D_ + dc * 16 + l16] = o[dc][r] * rinv[r];
    }
}

// ---------------- launch ----------------

extern "C" void kernel_launch(void* const* d_in, const int* in_sizes, int n_in,
                              void* d_out, int out_size, void* d_ws, size_t ws_size,
                              hipStream_t stream) {
  const float* x   = (const float*)d_in[0];
  const float* Wq  = (const float*)d_in[1];
  const float* bq  = (const float*)d_in[2];
  const float* Wk  = (const float*)d_in[3];
  const float* bk  = (const float*)d_in[4];
  const float* Wvd = (const float*)d_in[5];
  const float* bvd = (const float*)d_in[6];
  const float* Wvu = (const float*)d_in[7];
  const float* bvu = (const float*)d_in[8];
  float* out = (float*)d_out;

  char* ws = (char*)d_ws;
  unsigned short* xb   = (unsigned short*)(ws);                    // 8 MB
  unsigned short* Wt   = (unsigned short*)(ws + (8u << 20));       // 6 MB
  float*          ball = (float*)(ws + (14u << 20));               // 12 KB
  unsigned short* Qb   = (unsigned short*)(ws + (15u << 20));      // 8 MB
  unsigned short* Kb   = (unsigned short*)(ws + (23u << 20));      // 8 MB
  unsigned short* Vb   = (unsigned short*)(ws + (31u << 20));      // 8 MB (transposed)

  k_prep<<<8716, 256, 0, stream>>>(x, Wq, Wk, Wvd, Wvu, bq, bk, bvd, bvu, xb, Wt, ball);
  k_gemm_qkv<<<dim3(3072 / 128, 4096 / 128), 256, 0, stream>>>(xb, Wt, ball, Qb, Kb, Vb);
  k_attn<<<1024, 256, 0, stream>>>(Qb, Kb, Vb, out);
}

// Round 8
// 222.161 us; speedup vs baseline: 1.0073x; 1.0073x over previous
//
#include <hip/hip_runtime.h>
#include <stdint.h>

#define B_ 2
#define S_ 2048
#define E_ 1024
#define H_ 16
#define D_ 64
#define R_ 16

typedef short s16x8 __attribute__((ext_vector_type(8)));
typedef float f32x4 __attribute__((ext_vector_type(4)));

#define K1_ 0.045084220027780106f   // log2(e)/32
#define K0_ -28.853900817779268f    // -20*log2(e)

// fp32 -> bf16 bits, round-to-nearest (ties away)
__device__ __forceinline__ unsigned short f2bf(float f) {
  union { float f; unsigned u; } v; v.f = f;
  return (unsigned short)((v.u + 0x8000u) >> 16);
}

// async global->LDS, 16B per lane
__device__ __forceinline__ void load_lds16(const void* g, void* l) {
  __builtin_amdgcn_global_load_lds(
      (__attribute__((address_space(1))) void*)(g),
      (__attribute__((address_space(3))) void*)(l), 16, 0, 0);
}

// ---------------- unified prep kernel ----------------
// blocks [0,4096): x fp32->bf16
// blocks [4096,4608): Wq/Wk transpose -> Wt[(which,h,d),e]  (Wq scaled by K1)
// blocks [4608,8704): fused Wv = Wvd@Wvu -> Wt[(2,h,d),e]
// blocks [8704,8716): biases (bq scaled by K1)
__global__ void k_prep(const float* __restrict__ x,
                       const float* __restrict__ Wq, const float* __restrict__ Wk,
                       const float* __restrict__ Wvd, const float* __restrict__ Wvu,
                       const float* __restrict__ bq, const float* __restrict__ bk,
                       const float* __restrict__ bvd, const float* __restrict__ bvu,
                       unsigned short* __restrict__ xb, unsigned short* __restrict__ Wt,
                       float* __restrict__ ball) {
  __shared__ float T[64][65];
  const int blk = blockIdx.x;
  const int t = threadIdx.x;
  if (blk < 4096) {
    int i = (blk * 256 + t) * 4;
    float4 v = *(const float4*)(x + i);
    ushort4 o;
    o.x = f2bf(v.x); o.y = f2bf(v.y); o.z = f2bf(v.z); o.w = f2bf(v.w);
    *(ushort4*)(xb + i) = o;
  } else if (blk < 4608) {
    const int bb = blk - 4096;
    const int which = bb >> 8;
    const int h = (bb >> 4) & 15;
    const int et = bb & 15;
    const float scl = which ? 1.f : K1_;
    const float* src = (which ? Wk : Wq) + (h * E_ + et * 64) * D_;
#pragma unroll
    for (int pr = 0; pr < 4; ++pr) {
      const int row = pr * 16 + (t >> 4);
      const int col = (t & 15) * 4;
      float4 v = *(const float4*)(src + row * 64 + col);
      T[row][col] = v.x; T[row][col + 1] = v.y; T[row][col + 2] = v.z; T[row][col + 3] = v.w;
    }
    __syncthreads();
#pragma unroll
    for (int pr = 0; pr < 4; ++pr) {
      const int d = pr * 16 + (t >> 4);
      const int ec = (t & 15) * 4;
      ushort4 o;
      o.x = f2bf(T[ec][d] * scl); o.y = f2bf(T[ec + 1][d] * scl);
      o.z = f2bf(T[ec + 2][d] * scl); o.w = f2bf(T[ec + 3][d] * scl);
      *(ushort4*)(Wt + ((which << 10) + h * 64 + d) * 1024 + et * 64 + ec) = o;
    }
  } else if (blk < 8704) {
    const int idx = (blk - 4608) * 256 + t;  // 1M
    const int row = idx >> 10;                // h*64+d
    const int e = idx & 1023;
    const int h = row >> 6, d = row & 63;
    const float4* wd4 = (const float4*)(Wvd + (h << 14) + e * 16);
    const float* wu = Wvu + h * R_ * D_ + d;
    float acc = 0.f;
#pragma unroll
    for (int r4 = 0; r4 < 4; ++r4) {
      float4 a = wd4[r4];
      acc += a.x * wu[(r4 * 4 + 0) * 64];
      acc += a.y * wu[(r4 * 4 + 1) * 64];
      acc += a.z * wu[(r4 * 4 + 2) * 64];
      acc += a.w * wu[(r4 * 4 + 3) * 64];
    }
    Wt[(2048 + row) * 1024 + e] = f2bf(acc);
  } else {
    int n = (blk - 8704) * 256 + t;  // 3072
    int which = n >> 10;
    int hd = n & 1023;
    int h = hd >> 6, d = hd & 63;
    float v;
    if (which == 0) v = bq[hd] * K1_;
    else if (which == 1) v = bk[hd];
    else {
      v = bvu[hd];
#pragma unroll
      for (int r = 0; r < R_; ++r) v += bvd[h * R_ + r] * Wvu[(h * R_ + r) * D_ + d];
    }
    ball[n] = v;
  }
}

// ---------------- fused QKV GEMM (R4-proven structure) ----------------
// cols [0,1024): Q*K1 -> (bh, s, d); [1024,2048): K -> (bh, s, d);
// [2048,3072): V -> transposed (bh, d, s)

__global__ __launch_bounds__(256, 2) void k_gemm_qkv(
    const unsigned short* __restrict__ X, const unsigned short* __restrict__ Wt,
    const float* __restrict__ ball,
    unsigned short* __restrict__ Qb, unsigned short* __restrict__ Kb,
    unsigned short* __restrict__ Vb) {
  __shared__ unsigned short As[128 * 32];
  __shared__ unsigned short Bs[128 * 32];
  const int tid = threadIdx.x;
  const int lane = tid & 63, wave = tid >> 6;
  const int quad = lane >> 4, l16 = lane & 15;
  const int mBase = blockIdx.y * 128, nBase = blockIdx.x * 128;
  const int wm = (wave & 1) * 64, wn = (wave >> 1) * 64;
  const int lrow = lane >> 2, lcol = (lane & 3) * 8;

  f32x4 acc[4][4];
#pragma unroll
  for (int mi = 0; mi < 4; ++mi)
#pragma unroll
    for (int ni = 0; ni < 4; ++ni) acc[mi][ni] = (f32x4){0.f, 0.f, 0.f, 0.f};

  for (int k0 = 0; k0 < E_; k0 += 32) {
#pragma unroll
    for (int i = 0; i < 2; ++i) {
      const int r0 = __builtin_amdgcn_readfirstlane((wave + i * 4) * 16);
      load_lds16(X + (mBase + r0 + lrow) * E_ + k0 + lcol, &As[r0 * 32]);
      load_lds16(Wt + (nBase + r0 + lrow) * E_ + k0 + lcol, &Bs[r0 * 32]);
    }
    __syncthreads();
    s16x8 af[4], bfr[4];
#pragma unroll
    for (int mi = 0; mi < 4; ++mi)
      af[mi] = *(const s16x8*)&As[(wm + mi * 16 + l16) * 32 + quad * 8];
#pragma unroll
    for (int ni = 0; ni < 4; ++ni)
      bfr[ni] = *(const s16x8*)&Bs[(wn + ni * 16 + l16) * 32 + quad * 8];
#pragma unroll
    for (int mi = 0; mi < 4; ++mi)
#pragma unroll
      for (int ni = 0; ni < 4; ++ni)
        acc[mi][ni] = __builtin_amdgcn_mfma_f32_16x16x32_bf16(af[mi], bfr[ni], acc[mi][ni], 0, 0, 0);
    __syncthreads();
  }

  const int which = nBase >> 10;  // uniform per block
#pragma unroll
  for (int ni = 0; ni < 4; ++ni) {
    const int n = nBase + wn + ni * 16 + l16;
    const int nh = n & 1023;
    const int h = nh >> 6, d = nh & 63;
    const float bias = ball[n];
#pragma unroll
    for (int mi = 0; mi < 4; ++mi) {
      const int m0 = mBase + wm + mi * 16 + quad * 4;
      const int b = m0 >> 11;
      const int s = m0 & 2047;
      const int bh = b * H_ + h;
      if (which == 2) {
        ushort4 pk;
        pk.x = f2bf(acc[mi][ni][0] + bias);
        pk.y = f2bf(acc[mi][ni][1] + bias);
        pk.z = f2bf(acc[mi][ni][2] + bias);
        pk.w = f2bf(acc[mi][ni][3] + bias);
        *(ushort4*)(Vb + (bh * D_ + d) * S_ + s) = pk;  // transposed store
      } else {
        unsigned short* dst = (which == 0 ? Qb : Kb) + (bh * S_ + s) * D_ + d;
#pragma unroll
        for (int r = 0; r < 4; ++r) dst[r * D_] = f2bf(acc[mi][ni][r] + bias);
      }
    }
  }
}

// ---------------- flash attention (anti-causal: attend t >= s) ----------------
// Wave owns 16 q-rows. K double-buffered in LDS (DMA issued after each barrier,
// drained at the NEXT barrier -> full tile of flight). V prefetched into
// REGISTERS one tile ahead, also issued after the barrier -> full tile of
// flight (fixes the R7 zero-flight drain). No Vs in LDS. Loop unrolled by 2
// for the vbA/vbB register rotation. 1024 blocks, chunk-balanced mapping,
// 4 blocks/CU. Fixed-max softmax: Q pre-scaled by K1, QK C-initialized w/ K0.

__global__ __launch_bounds__(256, 4) void k_attn(
    const unsigned short* __restrict__ Qb, const unsigned short* __restrict__ Kb,
    const unsigned short* __restrict__ Vb, float* __restrict__ out) {
  __shared__ unsigned short Ks[2][2 * 64 * 32];   // [buf][64 k-rows x 64 d]
  __shared__ unsigned short Ps[4][2][16][40];     // [wave][kc][q-row][32 t + pad]
  const int tid = threadIdx.x;
  const int lane = tid & 63, wave = tid >> 6;
  const int quad = lane >> 4, l16 = lane & 15;
  const int chunk = blockIdx.x >> 8;
  const int j = blockIdx.x & 255;
  int qt = j >> 3;
  if (chunk & 1) qt = 31 - qt;
  const int bh = (j & 7) + 8 * chunk;
  const int q0 = qt * 64;
  const int lrow = lane >> 2, lcol = (lane & 3) * 8;
  const int r0 = __builtin_amdgcn_readfirstlane(wave * 16);
  const f32x4 kvec = {K0_, K0_, K0_, K0_};

  s16x8 qf[2];
  {
    const unsigned short* qp = Qb + (bh * S_ + q0 + wave * 16 + l16) * D_ + quad * 8;
    qf[0] = *(const s16x8*)qp;
    qf[1] = *(const s16x8*)(qp + 32);
  }
  f32x4 o[4];
#pragma unroll
  for (int dc = 0; dc < 4; ++dc) o[dc] = (f32x4){0.f, 0.f, 0.f, 0.f};
  float l_acc[4] = {0.f, 0.f, 0.f, 0.f};

#define LOAD_V(kt_, vb_)                                                       \
  {                                                                            \
    const unsigned short* vp_ = Vb + (bh * D_ + l16) * S_ + (kt_) * 64;        \
    _Pragma("unroll")                                                          \
    for (int kc = 0; kc < 2; ++kc)                                             \
      _Pragma("unroll")                                                        \
      for (int dc = 0; dc < 4; ++dc)                                           \
        vb_[kc][dc] = *(const s16x8*)(vp_ + (dc * 16) * S_ + kc * 32 + quad * 8); \
  }

#define DMA_K(kt_, b_)                                                         \
  {                                                                            \
    _Pragma("unroll")                                                          \
    for (int hdc = 0; hdc < 2; ++hdc)                                          \
      load_lds16(Kb + (bh * S_ + (kt_) * 64 + r0 + lrow) * D_ + hdc * 32 + lcol, \
                 &Ks[b_][hdc * 2048 + r0 * 32]);                               \
  }

#define TILE(kt_, b_, vb_, diag_)                                              \
  {                                                                            \
    f32x4 sc[4];                                                               \
    _Pragma("unroll")                                                          \
    for (int tc = 0; tc < 4; ++tc) {                                           \
      f32x4 a_ = __builtin_amdgcn_mfma_f32_16x16x32_bf16(                      \
          qf[0], *(const s16x8*)&Ks[b_][(tc * 16 + l16) * 32 + quad * 8],      \
          kvec, 0, 0, 0);                                                      \
      sc[tc] = __builtin_amdgcn_mfma_f32_16x16x32_bf16(                        \
          qf[1], *(const s16x8*)&Ks[b_][2048 + (tc * 16 + l16) * 32 + quad * 8], \
          a_, 0, 0, 0);                                                        \
    }                                                                          \
    if (diag_) {                                                               \
      _Pragma("unroll")                                                        \
      for (int tc = 0; tc < 4; ++tc)                                           \
        _Pragma("unroll")                                                      \
        for (int r = 0; r < 4; ++r) {                                          \
          const int t_ = tc * 16 + l16;                                        \
          const int q_ = wave * 16 + quad * 4 + r;                             \
          if (t_ < q_) sc[tc][r] = -200.f;                                     \
        }                                                                      \
    }                                                                          \
    _Pragma("unroll")                                                          \
    for (int tc = 0; tc < 4; ++tc)                                             \
      _Pragma("unroll")                                                        \
      for (int r = 0; r < 4; ++r) {                                            \
        float p_ = exp2f(sc[tc][r]);                                           \
        l_acc[r] += p_;                                                        \
        Ps[wave][tc >> 1][quad * 4 + r][(tc & 1) * 16 + l16] =                 \
            (unsigned short)(__float_as_uint(p_) >> 16);                       \
      }                                                                        \
    _Pragma("unroll")                                                          \
    for (int kc = 0; kc < 2; ++kc) {                                           \
      s16x8 pf_ = *(const s16x8*)&Ps[wave][kc][l16][quad * 8];                 \
      _Pragma("unroll")                                                        \
      for (int dc = 0; dc < 4; ++dc)                                           \
        o[dc] = __builtin_amdgcn_mfma_f32_16x16x32_bf16(pf_, vb_[kc][dc],      \
                                                        o[dc], 0, 0, 0);       \
    }                                                                          \
  }

  s16x8 vbA[2][4], vbB[2][4];
  // prologue: stage K(qt) -> Ks[0], V(qt) -> vbA (both in flight)
  DMA_K(qt, 0);
  LOAD_V(qt, vbA);

  int kt = qt;
  while (kt + 1 < 32) {
    __syncthreads();            // drains K-dma(kt)->Ks[0-phase], V(kt)->regs
    DMA_K(kt + 1, 1);
    LOAD_V(kt + 1, vbB);
    TILE(kt, 0, vbA, (kt == qt));
    __syncthreads();            // drains K-dma(kt+1), V(kt+1)
    if (kt + 2 < 32) {
      DMA_K(kt + 2, 0);
      LOAD_V(kt + 2, vbA);
    }
    TILE(kt + 1, 1, vbB, false);
    kt += 2;
  }
  if (kt < 32) {                // leftover single tile (vbA / Ks[0] staged)
    __syncthreads();
    TILE(kt, 0, vbA, (kt == qt));
  }

#undef LOAD_V
#undef DMA_K
#undef TILE

  // epilogue: reduce l over the 16 lanes holding each row's t-slices
#pragma unroll
  for (int off = 1; off < 16; off <<= 1)
#pragma unroll
    for (int r = 0; r < 4; ++r) l_acc[r] += __shfl_xor(l_acc[r], off);
  float rinv[4];
#pragma unroll
  for (int r = 0; r < 4; ++r) rinv[r] = 1.f / l_acc[r];

  const int b = bh >> 4, h = bh & 15;
#pragma unroll
  for (int dc = 0; dc < 4; ++dc)
#pragma unroll
    for (int r = 0; r < 4; ++r) {
      const int s = q0 + wave * 16 + quad * 4 + r;
      out[(b * S_ + s) * (H_ * D_) + h * D_ + dc * 16 + l16] = o[dc][r] * rinv[r];
    }
}

// ---------------- launch ----------------

extern "C" void kernel_launch(void* const* d_in, const int* in_sizes, int n_in,
                              void* d_out, int out_size, void* d_ws, size_t ws_size,
                              hipStream_t stream) {
  const float* x   = (const float*)d_in[0];
  const float* Wq  = (const float*)d_in[1];
  const float* bq  = (const float*)d_in[2];
  const float* Wk  = (const float*)d_in[3];
  const float* bk  = (const float*)d_in[4];
  const float* Wvd = (const float*)d_in[5];
  const float* bvd = (const float*)d_in[6];
  const float* Wvu = (const float*)d_in[7];
  const float* bvu = (const float*)d_in[8];
  float* out = (float*)d_out;

  char* ws = (char*)d_ws;
  unsigned short* xb   = (unsigned short*)(ws);                    // 8 MB
  unsigned short* Wt   = (unsigned short*)(ws + (8u << 20));       // 6 MB
  float*          ball = (float*)(ws + (14u << 20));               // 12 KB
  unsigned short* Qb   = (unsigned short*)(ws + (15u << 20));      // 8 MB
  unsigned short* Kb   = (unsigned short*)(ws + (23u << 20));      // 8 MB
  unsigned short* Vb   = (unsigned short*)(ws + (31u << 20));      // 8 MB (transposed)

  k_prep<<<8716, 256, 0, stream>>>(x, Wq, Wk, Wvd, Wvu, bq, bk, bvd, bvu, xb, Wt, ball);
  k_gemm_qkv<<<dim3(3072 / 128, 4096 / 128), 256, 0, stream>>>(xb, Wt, ball, Qb, Kb, Vb);
  k_attn<<<1024, 256, 0, stream>>>(Qb, Kb, Vb, out);
}

// Round 9
// 171.704 us; speedup vs baseline: 1.3033x; 1.2939x over previous
//
#include <hip/hip_runtime.h>
#include <stdint.h>

#define B_ 2
#define S_ 2048
#define E_ 1024
#define H_ 16
#define D_ 64
#define R_ 16

typedef short s16x8 __attribute__((ext_vector_type(8)));
typedef float f32x4 __attribute__((ext_vector_type(4)));

#define K1_ 0.045084220027780106f   // log2(e)/32
#define K0_ -28.853900817779268f    // -20*log2(e)

// fp32 -> bf16 bits, round-to-nearest (ties away)
__device__ __forceinline__ unsigned short f2bf(float f) {
  union { float f; unsigned u; } v; v.f = f;
  return (unsigned short)((v.u + 0x8000u) >> 16);
}

// async global->LDS, 16B per lane
__device__ __forceinline__ void load_lds16(const void* g, void* l) {
  __builtin_amdgcn_global_load_lds(
      (__attribute__((address_space(1))) void*)(g),
      (__attribute__((address_space(3))) void*)(l), 16, 0, 0);
}

// ---------------- unified prep kernel ----------------
// blocks [0,4096): x fp32->bf16
// blocks [4096,4608): Wq/Wk transpose -> Wt[(which,h,d),e]  (Wq scaled by K1)
// blocks [4608,8704): fused Wv = Wvd@Wvu -> Wt[(2,h,d),e]
// blocks [8704,8716): biases (bq scaled by K1)
__global__ void k_prep(const float* __restrict__ x,
                       const float* __restrict__ Wq, const float* __restrict__ Wk,
                       const float* __restrict__ Wvd, const float* __restrict__ Wvu,
                       const float* __restrict__ bq, const float* __restrict__ bk,
                       const float* __restrict__ bvd, const float* __restrict__ bvu,
                       unsigned short* __restrict__ xb, unsigned short* __restrict__ Wt,
                       float* __restrict__ ball) {
  __shared__ float T[64][65];
  const int blk = blockIdx.x;
  const int t = threadIdx.x;
  if (blk < 4096) {
    int i = (blk * 256 + t) * 4;
    float4 v = *(const float4*)(x + i);
    ushort4 o;
    o.x = f2bf(v.x); o.y = f2bf(v.y); o.z = f2bf(v.z); o.w = f2bf(v.w);
    *(ushort4*)(xb + i) = o;
  } else if (blk < 4608) {
    const int bb = blk - 4096;
    const int which = bb >> 8;
    const int h = (bb >> 4) & 15;
    const int et = bb & 15;
    const float scl = which ? 1.f : K1_;
    const float* src = (which ? Wk : Wq) + (h * E_ + et * 64) * D_;
#pragma unroll
    for (int pr = 0; pr < 4; ++pr) {
      const int row = pr * 16 + (t >> 4);
      const int col = (t & 15) * 4;
      float4 v = *(const float4*)(src + row * 64 + col);
      T[row][col] = v.x; T[row][col + 1] = v.y; T[row][col + 2] = v.z; T[row][col + 3] = v.w;
    }
    __syncthreads();
#pragma unroll
    for (int pr = 0; pr < 4; ++pr) {
      const int d = pr * 16 + (t >> 4);
      const int ec = (t & 15) * 4;
      ushort4 o;
      o.x = f2bf(T[ec][d] * scl); o.y = f2bf(T[ec + 1][d] * scl);
      o.z = f2bf(T[ec + 2][d] * scl); o.w = f2bf(T[ec + 3][d] * scl);
      *(ushort4*)(Wt + ((which << 10) + h * 64 + d) * 1024 + et * 64 + ec) = o;
    }
  } else if (blk < 8704) {
    const int idx = (blk - 4608) * 256 + t;  // 1M
    const int row = idx >> 10;                // h*64+d
    const int e = idx & 1023;
    const int h = row >> 6, d = row & 63;
    const float4* wd4 = (const float4*)(Wvd + (h << 14) + e * 16);
    const float* wu = Wvu + h * R_ * D_ + d;
    float acc = 0.f;
#pragma unroll
    for (int r4 = 0; r4 < 4; ++r4) {
      float4 a = wd4[r4];
      acc += a.x * wu[(r4 * 4 + 0) * 64];
      acc += a.y * wu[(r4 * 4 + 1) * 64];
      acc += a.z * wu[(r4 * 4 + 2) * 64];
      acc += a.w * wu[(r4 * 4 + 3) * 64];
    }
    Wt[(2048 + row) * 1024 + e] = f2bf(acc);
  } else {
    int n = (blk - 8704) * 256 + t;  // 3072
    int which = n >> 10;
    int hd = n & 1023;
    int h = hd >> 6, d = hd & 63;
    float v;
    if (which == 0) v = bq[hd] * K1_;
    else if (which == 1) v = bk[hd];
    else {
      v = bvu[hd];
#pragma unroll
      for (int r = 0; r < R_; ++r) v += bvd[h * R_ + r] * Wvu[(h * R_ + r) * D_ + d];
    }
    ball[n] = v;
  }
}

// ---------------- fused QKV GEMM (R4-proven structure, untouched) ----------------
// cols [0,1024): Q*K1 -> (bh, s, d); [1024,2048): K -> (bh, s, d);
// [2048,3072): V -> transposed (bh, d, s)

__global__ __launch_bounds__(256, 2) void k_gemm_qkv(
    const unsigned short* __restrict__ X, const unsigned short* __restrict__ Wt,
    const float* __restrict__ ball,
    unsigned short* __restrict__ Qb, unsigned short* __restrict__ Kb,
    unsigned short* __restrict__ Vb) {
  __shared__ unsigned short As[128 * 32];
  __shared__ unsigned short Bs[128 * 32];
  const int tid = threadIdx.x;
  const int lane = tid & 63, wave = tid >> 6;
  const int quad = lane >> 4, l16 = lane & 15;
  const int mBase = blockIdx.y * 128, nBase = blockIdx.x * 128;
  const int wm = (wave & 1) * 64, wn = (wave >> 1) * 64;
  const int lrow = lane >> 2, lcol = (lane & 3) * 8;

  f32x4 acc[4][4];
#pragma unroll
  for (int mi = 0; mi < 4; ++mi)
#pragma unroll
    for (int ni = 0; ni < 4; ++ni) acc[mi][ni] = (f32x4){0.f, 0.f, 0.f, 0.f};

  for (int k0 = 0; k0 < E_; k0 += 32) {
#pragma unroll
    for (int i = 0; i < 2; ++i) {
      const int r0 = __builtin_amdgcn_readfirstlane((wave + i * 4) * 16);
      load_lds16(X + (mBase + r0 + lrow) * E_ + k0 + lcol, &As[r0 * 32]);
      load_lds16(Wt + (nBase + r0 + lrow) * E_ + k0 + lcol, &Bs[r0 * 32]);
    }
    __syncthreads();
    s16x8 af[4], bfr[4];
#pragma unroll
    for (int mi = 0; mi < 4; ++mi)
      af[mi] = *(const s16x8*)&As[(wm + mi * 16 + l16) * 32 + quad * 8];
#pragma unroll
    for (int ni = 0; ni < 4; ++ni)
      bfr[ni] = *(const s16x8*)&Bs[(wn + ni * 16 + l16) * 32 + quad * 8];
#pragma unroll
    for (int mi = 0; mi < 4; ++mi)
#pragma unroll
      for (int ni = 0; ni < 4; ++ni)
        acc[mi][ni] = __builtin_amdgcn_mfma_f32_16x16x32_bf16(af[mi], bfr[ni], acc[mi][ni], 0, 0, 0);
    __syncthreads();
  }

  const int which = nBase >> 10;  // uniform per block
#pragma unroll
  for (int ni = 0; ni < 4; ++ni) {
    const int n = nBase + wn + ni * 16 + l16;
    const int nh = n & 1023;
    const int h = nh >> 6, d = nh & 63;
    const float bias = ball[n];
#pragma unroll
    for (int mi = 0; mi < 4; ++mi) {
      const int m0 = mBase + wm + mi * 16 + quad * 4;
      const int b = m0 >> 11;
      const int s = m0 & 2047;
      const int bh = b * H_ + h;
      if (which == 2) {
        ushort4 pk;
        pk.x = f2bf(acc[mi][ni][0] + bias);
        pk.y = f2bf(acc[mi][ni][1] + bias);
        pk.z = f2bf(acc[mi][ni][2] + bias);
        pk.w = f2bf(acc[mi][ni][3] + bias);
        *(ushort4*)(Vb + (bh * D_ + d) * S_ + s) = pk;  // transposed store
      } else {
        unsigned short* dst = (which == 0 ? Qb : Kb) + (bh * S_ + s) * D_ + d;
#pragma unroll
        for (int r = 0; r < 4; ++r) dst[r * D_] = f2bf(acc[mi][ni][r] + bias);
      }
    }
  }
}

// ---------------- flash attention (anti-causal: attend t >= s) ----------------
// K AND V double-buffered in LDS via DMA; ONE barrier per tile, prefetch for
// kt+1 issued right after the barrier -> a full tile of compute in flight
// before its drain at the next barrier. Ps shrunk to a single 32-t half
// (per-wave private, reused across the two halves) -> LDS 37.1 KB -> 4
// blocks/CU. 1024 blocks, chunk-balanced qt mapping (66 tile-units per CU).
// Fixed-max softmax: Q pre-scaled by K1, QK C-initialized with K0.

__global__ __launch_bounds__(256, 4) void k_attn(
    const unsigned short* __restrict__ Qb, const unsigned short* __restrict__ Kb,
    const unsigned short* __restrict__ Vb, float* __restrict__ out) {
  __shared__ unsigned short Ks[2][2 * 64 * 32];   // [buf][dhalf][64 k][32 d]
  __shared__ unsigned short Vs[2][2 * 64 * 32];   // [buf][thalf][64 d][32 t]
  __shared__ unsigned short Ps[4][16][40];        // [wave][q-row][32 t + pad]
  const int tid = threadIdx.x;
  const int lane = tid & 63, wave = tid >> 6;
  const int quad = lane >> 4, l16 = lane & 15;
  const int chunk = blockIdx.x >> 8;
  const int j = blockIdx.x & 255;
  int qt = j >> 3;
  if (chunk & 1) qt = 31 - qt;
  const int bh = (j & 7) + 8 * chunk;
  const int q0 = qt * 64;
  const int lrow = lane >> 2, lcol = (lane & 3) * 8;
  const int r0 = __builtin_amdgcn_readfirstlane(wave * 16);
  const f32x4 kvec = {K0_, K0_, K0_, K0_};

  s16x8 qf[2];
  {
    const unsigned short* qp = Qb + (bh * S_ + q0 + wave * 16 + l16) * D_ + quad * 8;
    qf[0] = *(const s16x8*)qp;
    qf[1] = *(const s16x8*)(qp + 32);
  }
  f32x4 o[4];
#pragma unroll
  for (int dc = 0; dc < 4; ++dc) o[dc] = (f32x4){0.f, 0.f, 0.f, 0.f};
  float l_acc[4] = {0.f, 0.f, 0.f, 0.f};

#define DMA_KV(kt_, b_)                                                          \
  {                                                                              \
    _Pragma("unroll")                                                            \
    for (int hdc = 0; hdc < 2; ++hdc) {                                          \
      load_lds16(Kb + (bh * S_ + (kt_) * 64 + r0 + lrow) * D_ + hdc * 32 + lcol, \
                 &Ks[b_][hdc * 2048 + r0 * 32]);                                 \
      load_lds16(Vb + (bh * D_ + r0 + lrow) * S_ + (kt_) * 64 + hdc * 32 + lcol, \
                 &Vs[b_][hdc * 2048 + r0 * 32]);                                 \
    }                                                                            \
  }

  // prologue: stage tile qt into buffer 0
  DMA_KV(qt, 0);

  int buf = 0;
  for (int kt = qt; kt < S_ / 64; ++kt) {
    __syncthreads();  // Ks/Vs[buf] DMA drained; prior reads of buf^1 done
    if (kt + 1 < S_ / 64) DMA_KV(kt + 1, buf ^ 1);

    const bool diag = (kt == qt);
#pragma unroll
    for (int kc = 0; kc < 2; ++kc) {
      // scores for this 32-t half (tc = kc*2 + tcc), C-init with K0
#pragma unroll
      for (int tcc = 0; tcc < 2; ++tcc) {
        const int tc = kc * 2 + tcc;
        f32x4 a = __builtin_amdgcn_mfma_f32_16x16x32_bf16(
            qf[0], *(const s16x8*)&Ks[buf][(tc * 16 + l16) * 32 + quad * 8], kvec, 0, 0, 0);
        f32x4 sc = __builtin_amdgcn_mfma_f32_16x16x32_bf16(
            qf[1], *(const s16x8*)&Ks[buf][2048 + (tc * 16 + l16) * 32 + quad * 8], a, 0, 0, 0);
        if (diag) {
#pragma unroll
          for (int r = 0; r < 4; ++r) {
            const int t = tc * 16 + l16;
            const int q = wave * 16 + quad * 4 + r;
            if (t < q) sc[r] = -200.f;
          }
        }
#pragma unroll
        for (int r = 0; r < 4; ++r) {
          float p = exp2f(sc[r]);
          l_acc[r] += p;
          Ps[wave][quad * 4 + r][tcc * 16 + l16] =
              (unsigned short)(__float_as_uint(p) >> 16);
        }
      }
      // PV for this half: P A-frag from per-wave LDS (no barrier)
      s16x8 pf = *(const s16x8*)&Ps[wave][l16][quad * 8];
#pragma unroll
      for (int dc = 0; dc < 4; ++dc) {
        s16x8 vb = *(const s16x8*)&Vs[buf][kc * 2048 + (dc * 16 + l16) * 32 + quad * 8];
        o[dc] = __builtin_amdgcn_mfma_f32_16x16x32_bf16(pf, vb, o[dc], 0, 0, 0);
      }
    }
    buf ^= 1;
  }
#undef DMA_KV

  // epilogue: reduce l over the 16 lanes holding each row's t-slices
#pragma unroll
  for (int off = 1; off < 16; off <<= 1)
#pragma unroll
    for (int r = 0; r < 4; ++r) l_acc[r] += __shfl_xor(l_acc[r], off);
  float rinv[4];
#pragma unroll
  for (int r = 0; r < 4; ++r) rinv[r] = 1.f / l_acc[r];

  const int b = bh >> 4, h = bh & 15;
#pragma unroll
  for (int dc = 0; dc < 4; ++dc)
#pragma unroll
    for (int r = 0; r < 4; ++r) {
      const int s = q0 + wave * 16 + quad * 4 + r;
      out[(b * S_ + s) * (H_ * D_) + h * D_ + dc * 16 + l16] = o[dc][r] * rinv[r];
    }
}

// ---------------- launch ----------------

extern "C" void kernel_launch(void* const* d_in, const int* in_sizes, int n_in,
                              void* d_out, int out_size, void* d_ws, size_t ws_size,
                              hipStream_t stream) {
  const float* x   = (const float*)d_in[0];
  const float* Wq  = (const float*)d_in[1];
  const float* bq  = (const float*)d_in[2];
  const float* Wk  = (const float*)d_in[3];
  const float* bk  = (const float*)d_in[4];
  const float* Wvd = (const float*)d_in[5];
  const float* bvd = (const float*)d_in[6];
  const float* Wvu = (const float*)d_in[7];
  const float* bvu = (const float*)d_in[8];
  float* out = (float*)d_out;

  char* ws = (char*)d_ws;
  unsigned short* xb   = (unsigned short*)(ws);                    // 8 MB
  unsigned short* Wt   = (unsigned short*)(ws + (8u << 20));       // 6 MB
  float*          ball = (float*)(ws + (14u << 20));               // 12 KB
  unsigned short* Qb   = (unsigned short*)(ws + (15u << 20));      // 8 MB
  unsigned short* Kb   = (unsigned short*)(ws + (23u << 20));      // 8 MB
  unsigned short* Vb   = (unsigned short*)(ws + (31u << 20));      // 8 MB (transposed)

  k_prep<<<8716, 256, 0, stream>>>(x, Wq, Wk, Wvd, Wvu, bq, bk, bvd, bvu, xb, Wt, ball);
  k_gemm_qkv<<<dim3(3072 / 128, 4096 / 128), 256, 0, stream>>>(xb, Wt, ball, Qb, Kb, Vb);
  k_attn<<<1024, 256, 0, stream>>>(Qb, Kb, Vb, out);
}